// Round 5
// baseline (164.286 us; speedup 1.0000x reference)
//
#include <hip/hip_runtime.h>
#include <math.h>

#define NT 512   // threads per block; 512 blocks (one per channel h)

// Packed f32 pair: LLVM lowers arithmetic on this to v_pk_*_f32 (VOP3P) on gfx950.
typedef float v2 __attribute__((ext_vector_type(2)));

__device__ __forceinline__ v2 vrot(v2 a){ return (v2){-a.y, a.x}; }            // i*a
__device__ __forceinline__ v2 vconj(v2 a){ return (v2){a.x, -a.y}; }
__device__ __forceinline__ v2 vcmul(v2 a, v2 b){ return a.x*b + a.y*vrot(b); } // a*b: 2 pk_fma
__device__ __forceinline__ v2 vcmulc(v2 a, v2 b){                              // a*conj(b): 2 pk_fma
    return a.x*(v2){b.x, -b.y} + a.y*(v2){b.y, b.x};
}
__device__ __forceinline__ v2 vfma1(float s, v2 v, v2 acc){                    // acc + s*v: 1 pk_fma
    return (v2){ __builtin_fmaf(s, v.x, acc.x), __builtin_fmaf(s, v.y, acc.y) };
}

// XOR bank swizzle: float2 elements -> bank = (2e)%32 depends on e mod 16.
// SW changes bits 0-3 only => every address stays inside its aligned
// 512-element region (wave-ownership argument relies on this).
__device__ __forceinline__ int SW(int e){ return e ^ (((e>>5) ^ (e>>9)) & 15); }

// ---- cheap-address forms of SW for the structured access patterns ----
// Stride-512: e = tid + 512k (tid<512, k<8).  (e>>5)&15 = (tid>>5)&15 (k does
// not touch bits 5-8); (e>>9)&15 = k.  The xor value is <16 so it only flips
// bits 0-3 (inside tid), never interacting with +512k:
//   SW(tid+512k) = (tid ^ ((tid>>5)&15) ^ k) + 512k
// Byte address = (tbs ^ (k<<3)) + (k<<12) with tbs = (tid ^ ((tid>>5)&15))<<3:
// one v_xor with an inline constant + a ds immediate offset per access.
__device__ __forceinline__ v2& q512(v2* buf, int tbs, int k){
    return *(v2*)((char*)buf + ((tbs ^ (k<<3)) + (k<<12)));
}
// Upper half (+4096 elems): bit 12 adds 8 to (e>>9)&15 -> mask ^= 8 -> byte^=64,
// plus the +32768 byte offset (foldable into the ds immediate).
__device__ __forceinline__ v2& q512u(v2* buf, int tbs, int k){
    return *(v2*)((char*)buf + (((tbs ^ 64) ^ (k<<3)) + (k<<12) + 32768));
}

// base-8 digit reversal of a 12-bit index
__device__ __forceinline__ int d8r4(int x){
    return ((x&7)<<9) | (((x>>3)&7)<<6) | (((x>>6)&7)<<3) | ((x>>9)&7);
}
// base-8 digit reversal of a 9-bit index (thread id <-> butterfly block)
__device__ __forceinline__ int rev3(int t){
    return ((t&7)<<6) | (t&56) | ((t>>6)&7);
}

// ---- load one 7-twiddle row (padded to 8 v2 = 64B) from the global table.
__device__ __forceinline__ void load_row(const v2* twd, int rowIdx, v2 W[7]) {
    const float4* rp4 = (const float4*)(twd + rowIdx*8);
    float4 q0 = rp4[0], q1 = rp4[1], q2 = rp4[2], q3 = rp4[3];
    W[0]=(v2){q0.x,q0.y}; W[1]=(v2){q0.z,q0.w}; W[2]=(v2){q1.x,q1.y};
    W[3]=(v2){q1.z,q1.w}; W[4]=(v2){q2.x,q2.y}; W[5]=(v2){q2.z,q2.w};
    W[6]=(v2){q3.x,q3.y};
}

// ---- 8-point DFT, inverse sign (sigma=+1). y_m = sum_k t_k w^{mk}, w=e^{+i pi/4}
__device__ __forceinline__ void dft8_inv(v2 t[8], v2 y[8]) {
    const float RH = 0.70710678f;
    v2 p  = t[0]+t[4], m  = t[0]-t[4], q  = t[2]+t[6], r  = t[2]-t[6];
    v2 rr = vrot(r);
    v2 E0 = p+q, E2 = p-q, E1 = m+rr, E3 = m-rr;
    v2 p2 = t[1]+t[5], m2 = t[1]-t[5], q2 = t[3]+t[7], r2 = t[3]-t[7];
    v2 rr2 = vrot(r2);
    v2 O0 = p2+q2, O2 = p2-q2, O1 = m2+rr2, O3 = m2-rr2;
    v2 W1O = RH*(O1 + vrot(O1));        // w^1 * O1
    v2 W2O = vrot(O2);                  // w^2 = i
    v2 W3O = vrot(RH*(O3 + vrot(O3)));  // w^3 = i*w
    y[0] = E0 + O0;  y[4] = E0 - O0;
    y[1] = E1 + W1O; y[5] = E1 - W1O;
    y[2] = E2 + W2O; y[6] = E2 - W2O;
    y[3] = E3 + W3O; y[7] = E3 - W3O;
}

// ---- pruned: only y[0..3] (P7 epilogue discards the mirror half).
__device__ __forceinline__ void dft8_inv_lo4(v2 t[8], v2 y[4]) {
    const float RH = 0.70710678f;
    v2 p  = t[0]+t[4], m  = t[0]-t[4], q  = t[2]+t[6], r  = t[2]-t[6];
    v2 rr = vrot(r);
    v2 E0 = p+q, E2 = p-q, E1 = m+rr, E3 = m-rr;
    v2 p2 = t[1]+t[5], m2 = t[1]-t[5], q2 = t[3]+t[7], r2 = t[3]-t[7];
    v2 rr2 = vrot(r2);
    v2 O0 = p2+q2, O2 = p2-q2, O1 = m2+rr2, O3 = m2-rr2;
    v2 W1O = RH*(O1 + vrot(O1));
    v2 W2O = vrot(O2);
    v2 W3O = vrot(RH*(O3 + vrot(O3)));
    y[0] = E0 + O0;
    y[1] = E1 + W1O;
    y[2] = E2 + W2O;
    y[3] = E3 + W3O;
}

// ---- 8-point DFT, forward sign (sigma=-1).
__device__ __forceinline__ void dft8_fwd(v2 t[8], v2 y[8]) {
    const float RH = 0.70710678f;
    v2 p  = t[0]+t[4], m  = t[0]-t[4], q  = t[2]+t[6], r  = t[2]-t[6];
    v2 rr = vrot(r);
    v2 E0 = p+q, E2 = p-q, E1 = m-rr, E3 = m+rr;
    v2 p2 = t[1]+t[5], m2 = t[1]-t[5], q2 = t[3]+t[7], r2 = t[3]-t[7];
    v2 rr2 = vrot(r2);
    v2 O0 = p2+q2, O2 = p2-q2, O1 = m2-rr2, O3 = m2+rr2;
    v2 W1O = RH*(O1 - vrot(O1));          // w = (1-i)/sqrt2
    v2 W2O = (v2){O2.y, -O2.x};           // w^2 = -i
    v2 W3O = (-RH)*(O3 + vrot(O3));       // w^3 = (-1-i)/sqrt2
    y[0] = E0 + O0;  y[4] = E0 - O0;
    y[1] = E1 + W1O; y[5] = E1 - W1O;
    y[2] = E2 + W2O; y[6] = E2 - W2O;
    y[3] = E3 + W3O; y[7] = E3 - W3O;
}

// Wave-locality: for Q in {1,8,64}, thread t's butterfly addresses lie in the
// aligned 512-elem region [512*(t>>6), +512), owned exclusively by t's wave.
// LDS ops within a wave execute in issue order, so consecutive wave-local
// passes need only a compiler fence. BAR=true emits the block barrier.

// ---- radix-8 DIT pass, inverse, in-place over 4096 elems.
// Twiddle row W preloaded by the caller (so a chain of passes can issue all
// its global row-loads up front and hide the later rows' latency).
template<int Q, bool BAR>
__device__ __forceinline__ void r8_dit_inv(v2* buf, int tid, const v2 W[7]) {
    int j = tid & (Q-1);
    int base = 8*tid - 7*j;
    v2 t[8];
    #pragma unroll
    for (int k = 0; k < 8; ++k) t[k] = buf[SW(base + k*Q)];
    #pragma unroll
    for (int k = 0; k < 7; ++k) t[k+1] = vcmul(t[k+1], W[k]);
    v2 y[8];
    dft8_inv(t, y);
    #pragma unroll
    for (int m = 0; m < 8; ++m) buf[SW(base + m*Q)] = y[m];
    if (BAR) __syncthreads();
    else     __builtin_amdgcn_wave_barrier();
}

// ---- radix-8 DIF pass, forward, applied to BOTH 4096-halves of buf (serial:
// at the 64-VGPR budget the interleaved version spills — measured R2).
// Forward twiddles are conj of the preloaded table row (vcmulc).
// Q==1 uses the cheap-address form: base = 8*tid has low 3 bits zero, so the
// SW xor-mask is per-thread constant; upper half = mask^8 -> byte^64 (+32768,
// disjoint bits so xor/add commute and the 32768 folds into the ds immediate).
template<int Q, bool BAR>
__device__ __forceinline__ void r8_dif_fwd(v2* buf, int tid, const v2* W) {
    if (Q == 1) {
        const int b0  = tid << 6;                        // (8*tid)<<3  byte base
        const int bt  = tid << 3;                        // 8*tid       element base
        const int mLs = (((bt>>5) ^ (bt>>9)) & 15) << 3; // lower-half byte mask
        const int msU = (mLs ^ 64) + 32768;              // upper: ^64, +32768
        #pragma unroll 1
        for (int hh = 0; hh < 2; ++hh) {
            const int ms = hh ? msU : mLs;
            v2 t[8];
            #pragma unroll
            for (int k = 0; k < 8; ++k)
                t[k] = *(v2*)((char*)buf + ((b0 + (k<<3)) ^ ms));
            v2 y[8];
            dft8_fwd(t, y);
            #pragma unroll
            for (int m = 0; m < 8; ++m)
                *(v2*)((char*)buf + ((b0 + (m<<3)) ^ ms)) = y[m];
        }
        if (BAR) __syncthreads();
        else     __builtin_amdgcn_wave_barrier();
        return;
    }
    int j = tid & (Q-1);
    int baseL = 8*tid - 7*j;
    #pragma unroll 1
    for (int hh = 0; hh < 2; ++hh) {
        int base = baseL + (hh << 12);
        v2 t[8];
        #pragma unroll
        for (int k = 0; k < 8; ++k) t[k] = buf[SW(base + k*Q)];
        v2 y[8];
        dft8_fwd(t, y);
        #pragma unroll
        for (int k = 0; k < 7; ++k) y[k+1] = vcmulc(y[k+1], W[k]);
        #pragma unroll
        for (int m = 0; m < 8; ++m) buf[SW(base + m*Q)] = y[m];
    }
    if (BAR) __syncthreads();
    else     __builtin_amdgcn_wave_barrier();
}

// ---- merged prep kernel: blocks 0..H-1 compute per-(h,n) Cauchy weights;
//      the LAST block (blockIdx == H) fills the twiddle table
//      twd[j][k] = e^{+2pi i j(k+1)/4096}, j<512, k<7 (row padded to 8).
__global__ void __launch_bounds__(64)
s4_prep(const float* __restrict__ Lre, const float* __restrict__ Lim,
        const float* __restrict__ Pre, const float* __restrict__ Pim,
        const float* __restrict__ Bre, const float* __restrict__ Bim,
        const float* __restrict__ Cin,
        float* __restrict__ ws8, float* __restrict__ ws1,
        v2* __restrict__ twd)
{
    int b = blockIdx.x;
    if (b == (int)gridDim.x - 1) {
        // twiddle block: 64 threads x 8 rows
        const float fm = 6.2831853072f / 4096.0f;
        #pragma unroll
        for (int r = 0; r < 8; ++r) {
            int j = r*64 + (int)threadIdx.x;
            #pragma unroll
            for (int k = 0; k < 7; ++k) {
                float s, c; __sincosf(fm * (float)(j*(k+1)), &s, &c);
                twd[j*8 + k] = (v2){c, s};
            }
            twd[j*8 + 7] = (v2){1.0f, 0.0f};
        }
        return;
    }
    int idx = b*64 + threadIdx.x;   // h*64 + n
    float lre = fminf(Lre[idx], -1e-4f);
    float lim = Lim[idx];
    float pr = Pre[idx], pi = Pim[idx];
    float br = Bre[idx], bi = Bim[idx];
    float cr = Cin[2*idx], ci = Cin[2*idx+1];
    v2 cc = (v2){cr, -ci};
    v2 w00 = vcmul(cc, (v2){br, bi});     // conj(C)*B
    v2 w01 = vcmul(cc, (v2){pr, pi});     // conj(C)*P
    v2 w10 = vcmul((v2){pr,-pi}, (v2){br, bi});  // conj(P)*B
    float* o = ws8 + idx*8;
    o[0] = -lre;  o[1] = -lim;
    o[2] = w00.x; o[3] = w00.y;
    o[4] = w01.x; o[5] = w01.y;
    o[6] = w10.x; o[7] = w10.y;
    ws1[idx] = pr*pr + pi*pi;             // |P|^2 (real weight of k11)
}

// Fused S4 layer, one block per channel h. R3 structure + source-level
// software pipelining of the latency-bound uniform loads —
// (a) P1's n-loop rotates its scalar weight loads one group-of-2 ahead
//     (each group's s_load latency hides under the previous group's ~190
//     cycles of FMA work; all 4 waves/SIMD run this loop in lockstep, so
//     un-hidden scalar latency was stalling the whole SIMD);
// (b) the wave-local FFT chains issue BOTH twiddle rows' global loads up
//     front, hiding pass 2's row latency under pass 1.
// Prefetch indices wrap (&127 / &63): the last group's prefetched values are
// discarded, so any in-slice index is fine — avoids reading past the slice.
__global__ __attribute__((amdgpu_waves_per_eu(4, 4))) void __launch_bounds__(NT)
s4_fused(const float* __restrict__ u,
         const float* __restrict__ Din, const float* __restrict__ logstep,
         const float* __restrict__ ws8, const float* __restrict__ ws1,
         const v2* __restrict__ twd,
         float* __restrict__ out)
{
    __shared__ v2 buf[8192];   // 64 KB -> 2 blocks/CU
    const int tid = threadIdx.x;
    const int h = blockIdx.x;
    const int tbs = (tid ^ ((tid>>5) & 15)) << 3;   // stride-512 swizzle byte base

    const float step = expf(logstep[h]);
    const float tos  = 2.0f / step;
    const float hstep = 0.5f * step;
    const float* pp = ws8 + (h*64)*8;   // wave-uniform -> s_load
    const float* pw = ws1 + h*64;
    const float4* pp4 = (const float4*)pp;   // 2 float4 per n

    // ---- P1: Cauchy kernel; hp0's 4 results staged raw in LDS, hp1's kept in
    //      regs; then the P2 Q=1 butterfly runs in registers. ----
    v2 a4[4];
    #pragma unroll 1
    for (int hp = 0; hp < 2; ++hp) {
        float tv[4];
        v2 cf[4], k00[4], k01[4], k10[4], k11[4];
        const int lbase = hp*(4*NT);
        #pragma unroll
        for (int i = 0; i < 4; ++i) {
            int l = lbase + i*NT + tid;
            // reference's f32 angle; g = i*t with t = -tos*tan(ang/2) (exact identity:
            // (1-e^{i ang})/(1+e^{i ang}) = -i tan(ang/2))
            float ang = -6.2831855f * ((float)l * (1.0f/4096.0f));
            float sh, ch; __sincosf(0.5f*ang, &sh, &ch);
            float traw = -tos * sh * __builtin_amdgcn_rcpf(ch);
            float t = fminf(fmaxf(traw, -1e18f), 1e18f);   // guard cos==0 -> inf*0 NaN
            tv[i] = t;
            cf[i] = (v2){1.0f, t*hstep};                   // c = 1 - i*tan(ang/2)
            k00[i]=(v2)(0.0f); k01[i]=(v2)(0.0f); k10[i]=(v2)(0.0f); k11[i]=(v2)(0.0f);
        }
        // one n's worth of Cauchy accumulation (weights in scalar regs)
        auto cauchy_n = [&](float4 A, float4 B, float w11r) {
            float nlre = A.x, nlim = A.y;
            v2 w00 = (v2){A.z, A.w};
            v2 w01 = (v2){B.x, B.y};
            v2 w10 = (v2){B.z, B.w};
            float lre2 = nlre*nlre;
            #pragma unroll
            for (int i = 0; i < 4; ++i) {
                float s = tv[i] + nlim;                    // t - lim
                float inv = __builtin_amdgcn_rcpf(__builtin_fmaf(s, s, lre2));
                v2 p = (v2){nlre, s} * inv;                // d*inv, d = g - lam = (-lre, t-lim)
                v2 cp = (v2){p.x, -p.y};                   // 1/(g-lam)
                v2 rp = (v2){p.y,  p.x};
                k00[i] = vfma1(w00.y, rp, vfma1(w00.x, cp, k00[i]));
                k01[i] = vfma1(w01.y, rp, vfma1(w01.x, cp, k01[i]));
                k10[i] = vfma1(w10.y, rp, vfma1(w10.x, cp, k10[i]));
                k11[i] = vfma1(w11r,  cp, k11[i]);
            }
        };
        // Software-pipelined n-loop, groups of 2, loads rotated one group
        // ahead (wrapped indices; last prefetch is discarded).
        float4 ca0 = pp4[0], cb0 = pp4[1], ca1 = pp4[2], cb1 = pp4[3];
        float  cw0 = pw[0],  cw1 = pw[1];
        #pragma unroll 1
        for (int g = 0; g < 32; ++g) {
            const int nx = (4*g + 4) & 127;
            float4 na0 = pp4[nx],   nb0 = pp4[nx+1];
            float4 na1 = pp4[nx+2], nb1 = pp4[nx+3];
            float  nw0 = pw[(2*g+2) & 63], nw1 = pw[(2*g+3) & 63];
            cauchy_n(ca0, cb0, cw0);
            cauchy_n(ca1, cb1, cw1);
            ca0 = na0; cb0 = nb0; ca1 = na1; cb1 = nb1;
            cw0 = nw0; cw1 = nw1;
        }
        #pragma unroll
        for (int i = 0; i < 4; ++i) {
            v2 opk = (v2){1.0f + k11[i].x, k11[i].y};
            float iv = __builtin_amdgcn_rcpf(opk.x*opk.x + opk.y*opk.y);
            v2 r11 = vconj(opk) * iv;
            v2 t  = vcmul(vcmul(k01[i], r11), k10[i]);
            v2 res = vcmul(cf[i], k00[i] - t);             // atRoots[l], l = tid+512*(4hp+i)
            if (hp == 0) q512(buf, tbs, i) = res;          // stage raw
            else         a4[i] = res;
        }
    }
    {   // fused P2 Q=1 butterfly: t[k] = atRoots[tid + 512k]
        v2 t[8];
        #pragma unroll
        for (int k = 0; k < 4; ++k) t[k] = q512(buf, tbs, k);   // own raw stage
        #pragma unroll
        for (int k = 0; k < 4; ++k) t[4+k] = a4[k];
        __syncthreads();                    // all raw reads done before any butterfly write
        v2 y[8];
        dft8_inv(t, y);
        // scatter: tb8 = 8*rev3(tid) has low bits 0 -> SW mask is per-thread
        // constant; byte addr = (b8 + 8m) ^ m8s (2 VALU per store).
        const int tb8 = 8*rev3(tid);
        const int b8  = tb8 << 3;
        const int m8s = (((tb8>>5) ^ (tb8>>9)) & 15) << 3;
        #pragma unroll
        for (int m = 0; m < 8; ++m)
            *(v2*)((char*)buf + ((b8 + (m<<3)) ^ m8s)) = y[m];
    }
    __syncthreads();                        // Q1 scatter is cross-wave

    // ---- P2: ifft4096 middle passes (Q8->Q64 wave-local); both twiddle rows
    //      issued up front so the Q64 row's latency hides under the Q8 pass.
    {
        v2 W8[7], W64[7];
        load_row(twd, 64*(tid & 7),  W8);
        load_row(twd, 8*(tid & 63), W64);
        r8_dit_inv<8,  false>(buf, tid, W8);
        r8_dit_inv<64, true >(buf, tid, W64);
    }

    // ---- P3: fused P2-Q512 (DIT) + pack z = u + i*K + r2 stage + DIF-Q512.
    //      Thread tid reads {SW(tid+512k)}, writes the same lower-half slots
    //      (post-butterfly) + virgin upper half: no internal barrier needed. ----
    {
        v2 W[7];
        load_row(twd, tid, W);              // W[k] = W_4096^{+tid(k+1)}
        v2 t[8];
        #pragma unroll
        for (int k = 0; k < 8; ++k) t[k] = q512(buf, tbs, k);
        #pragma unroll
        for (int k = 0; k < 7; ++k) t[k+1] = vcmul(t[k+1], W[k]);
        v2 y[8];
        dft8_inv(t, y);                          // y[m].x = K*4096 at l = tid+512m
        float uval[8];
        const float* up = u + h*4096;
        #pragma unroll
        for (int m = 0; m < 8; ++m) uval[m] = up[tid + 512*m];
        // zL[k] = z[tid+512k], zU[k] = z[tid+512k]*W_8192^{-(tid+512k)}
        float s2, c2; __sincosf(-6.2831853072f/8192.0f*(float)tid, &s2, &c2);
        v2 cur0 = (v2){c2, s2};                  // W_8192^{-tid}
        const v2 C16n = (v2){0.92387953f, -0.38268343f};   // e^{-i pi/8} = W_8192^{-512}
        v2 zL[8], zU[8];
        {
            v2 cur = cur0;
            #pragma unroll
            for (int k = 0; k < 8; ++k) {
                zL[k] = (v2){uval[k], y[k].x * (1.0f/4096.0f)};
                zU[k] = vcmul(zL[k], cur);
                cur = vcmul(cur, C16n);
            }
        }
        // DIF-Q512 butterfly in registers; twiddles W_4096^{-tid*m} = conj(W[m-1])
        v2 s[8];
        dft8_fwd(zL, s);
        #pragma unroll
        for (int m = 1; m < 8; ++m) s[m] = vcmulc(s[m], W[m-1]);
        #pragma unroll
        for (int m = 0; m < 8; ++m) q512(buf, tbs, m) = s[m];
        dft8_fwd(zU, s);
        #pragma unroll
        for (int m = 1; m < 8; ++m) s[m] = vcmulc(s[m], W[m-1]);
        #pragma unroll
        for (int m = 0; m < 8; ++m) q512u(buf, tbs, m) = s[m];
    }
    __syncthreads();                        // Q512 writes are cross-wave for Q64

    // ---- P4: forward fft8192 remaining stages (Q512 in P3). Wave-local chain;
    //      barrier only after Q1. Z[k] lands at ((k&1)<<12) + d8r4(k>>1).
    //      Both rows issued up front (Q1 needs none).
    {
        v2 W64[7], W8f[7];
        load_row(twd, 8*(tid & 63), W64);
        load_row(twd, 64*(tid & 7),  W8f);
        r8_dif_fwd<64, false>(buf, tid, W64);
        r8_dif_fwd<8,  false>(buf, tid, W8f);
        r8_dif_fwd<1,  true >(buf, tid, (const v2*)nullptr);
    }

    // ---- P5: unpack + multiply + half-size-inverse pack, fused with P6 Q=1
    //      butterfly (v[i] for r = tid+512i are exactly block 8*rev3(tid)'s inputs).
    //      Index algebra: e(zc)=e(za)+4, e(zb)=e(zd)+4 (top-octal-digit of the
    //      pre-reversal index: +2048 -> reversed +4; r=0 fixed by cndmask). ----
    {
        float sb, cb; __sincosf(6.2831853072f/8192.0f*(float)tid, &sb, &cb);
        v2 cur = (v2){cb, sb};                   // W_8192^{+tid}
        const v2 C16p = (v2){0.92387953f, 0.38268343f};    // e^{+i pi/8}
        v2 v[8];
        #pragma unroll 1
        for (int i = 0; i < 8; ++i) {
            int r  = i*NT + tid;                 // 0..4095
            int par = (r&1)<<12;
            int e1 = par + d8r4(r>>1);           // za: Z[r]
            int e3 = e1 + 4;                     // zc: Z[r+4096]
            int k2c = 4096 - r;
            int e4 = ((k2c&1)<<12) + d8r4((k2c>>1)&4095);  // zd: Z[4096-r]
            int e2 = (r == 0) ? 0 : (e4 + 4);    // zb: Z[(8192-r)&8191]
            v2 za = buf[SW(e1)];
            v2 zb = buf[SW(e2)];
            v2 zc = buf[SW(e3)];
            v2 zd = buf[SW(e4)];
            v2 U1 = 0.5f*(za + vconj(zb));
            v2 K1 = -0.5f*vrot(za - vconj(zb));
            v2 Yr = vcmul(U1, K1);                               // Y[r]
            v2 U2 = 0.5f*(zc + vconj(zd));
            v2 K2 = -0.5f*vrot(zc - vconj(zd));
            v2 Ys = vcmul(U2, K2);                               // Y[r+4096]
            v[i] = (Yr + Ys) + vrot(vcmul(cur, Yr - Ys));        // A + i*W^r*(Yr-Ys)
            cur = vcmul(cur, C16p);
        }
        __syncthreads();                         // all gathers done before butterfly writes
        v2 y[8];
        dft8_inv(v, y);
        const int tb8 = 8*rev3(tid);
        const int b8  = tb8 << 3;
        const int m8s = (((tb8>>5) ^ (tb8>>9)) & 15) << 3;
        #pragma unroll
        for (int m = 0; m < 8; ++m)
            *(v2*)((char*)buf + ((b8 + (m<<3)) ^ m8s)) = y[m];
    }
    __syncthreads();                        // Q1 scatter is cross-wave

    // ---- P6: ifft4096 middle passes; rows issued up front ----
    {
        v2 W8[7], W64[7];
        load_row(twd, 64*(tid & 7),  W8);
        load_row(twd, 8*(tid & 63), W64);
        r8_dit_inv<8,  false>(buf, tid, W8);
        r8_dit_inv<64, true >(buf, tid, W64);
    }

    // ---- P7: fused P6-Q512 butterfly + epilogue. Only m<4 (first 4096 reals)
    //      survive the causal-conv truncation -> pruned DFT. ----
    {
        v2 W[7];
        load_row(twd, tid, W);
        v2 t[8];
        #pragma unroll
        for (int k = 0; k < 8; ++k) t[k] = q512(buf, tbs, k);
        #pragma unroll
        for (int k = 0; k < 7; ++k) t[k+1] = vcmul(t[k+1], W[k]);
        v2 y[4];
        dft8_inv_lo4(t, y);
        const float Dh = Din[h];
        const float sc = 1.0f / 8192.0f;
        const v2* u2 = (const v2*)(u + h*4096);
        v2*     out2 = (v2*)(out + h*4096);
        #pragma unroll
        for (int m = 0; m < 4; ++m) {
            int n = tid + 512*m;                 // v2-pair index -> outputs 2n, 2n+1
            out2[n] = sc*y[m] + Dh*u2[n];
        }
    }
}

extern "C" void kernel_launch(void* const* d_in, const int* in_sizes, int n_in,
                              void* d_out, int out_size, void* d_ws, size_t ws_size,
                              hipStream_t stream)
{
    const float* u       = (const float*)d_in[0];
    const float* Lre     = (const float*)d_in[1];
    const float* Lim     = (const float*)d_in[2];
    const float* Pre     = (const float*)d_in[3];
    const float* Pim     = (const float*)d_in[4];
    const float* Bre     = (const float*)d_in[5];
    const float* Bim     = (const float*)d_in[6];
    const float* Cin     = (const float*)d_in[7];
    const float* Din     = (const float*)d_in[8];
    const float* logstep = (const float*)d_in[9];
    float* out = (float*)d_out;
    const int H = in_sizes[8];  // D is [H,1]

    float* ws8 = (float*)d_ws;            // H*64*8 floats (1 MB)
    float* ws1 = ws8 + (size_t)H*64*8;    // H*64 floats (128 KB)
    v2*    twd = (v2*)(ws1 + (size_t)H*64);  // 512 rows x 8 v2 (32 KB); 64B-aligned

    // merged prep: blocks 0..H-1 per-(h,n) weights; block H fills twiddles
    hipLaunchKernelGGL(s4_prep, dim3(H + 1), dim3(64), 0, stream,
                       Lre, Lim, Pre, Pim, Bre, Bim, Cin, ws8, ws1, twd);
    hipLaunchKernelGGL(s4_fused, dim3(H), dim3(NT), 0, stream,
                       u, Din, logstep, ws8, ws1, twd, out);
}

// Round 6
// 147.496 us; speedup vs baseline: 1.1138x; 1.1138x over previous
//
#include <hip/hip_runtime.h>
#include <math.h>

#define NT 512   // threads per block; 512 blocks (one per channel h)

// Packed f32 pair. All hot complex math is expressed as explicit VOP3P
// (v_pk_*_f32) inline asm with op_sel/neg modifiers, so each complex
// multiply-accumulate is exactly 2 instructions and each rotate-combine
// (a +/- i*b) is 1 -- no shuffle/materialization overhead.
typedef float v2 __attribute__((ext_vector_type(2)));

__device__ __forceinline__ v2 vrot(v2 a){ return (v2){-a.y, a.x}; }            // i*a
__device__ __forceinline__ v2 vconj(v2 a){ return (v2){a.x, -a.y}; }

// a + i*b : (a.x - b.y, a.y + b.x) -- one v_pk_add_f32
__device__ __forceinline__ v2 pk_addrot(v2 a, v2 b){
    v2 d;
    asm("v_pk_add_f32 %0, %1, %2 op_sel:[0,1] op_sel_hi:[1,0] neg_lo:[0,1] neg_hi:[0,0]"
        : "=v"(d) : "v"(a), "v"(b));
    return d;
}
// a - i*b : (a.x + b.y, a.y - b.x)
__device__ __forceinline__ v2 pk_subrot(v2 a, v2 b){
    v2 d;
    asm("v_pk_add_f32 %0, %1, %2 op_sel:[0,1] op_sel_hi:[1,0] neg_lo:[0,0] neg_hi:[0,1]"
        : "=v"(d) : "v"(a), "v"(b));
    return d;
}
// complex a*b: mul (a.x*b.x, a.x*b.y) then fma (+= -a.y*b.y, += a.y*b.x)
__device__ __forceinline__ v2 vcmul(v2 a, v2 b){
    v2 d;
    asm("v_pk_mul_f32 %0, %1, %2 op_sel:[0,0] op_sel_hi:[0,1]"
        : "=v"(d) : "v"(a), "v"(b));
    asm("v_pk_fma_f32 %0, %1, %2, %0 op_sel:[1,1,0] op_sel_hi:[1,0,1] neg_lo:[0,1,0] neg_hi:[0,0,0]"
        : "+v"(d) : "v"(a), "v"(b));
    return d;
}
// complex a*conj(b)
__device__ __forceinline__ v2 vcmulc(v2 a, v2 b){
    v2 d;
    asm("v_pk_mul_f32 %0, %1, %2 op_sel:[0,0] op_sel_hi:[0,1] neg_lo:[0,0] neg_hi:[0,1]"
        : "=v"(d) : "v"(a), "v"(b));
    asm("v_pk_fma_f32 %0, %1, %2, %0 op_sel:[1,1,0] op_sel_hi:[1,0,1]"
        : "+v"(d) : "v"(a), "v"(b));
    return d;
}
// acc += w * (p.x, -p.y)  [i.e. w * (1/d)], complex w in SGPR pair: 2 pk_fma
__device__ __forceinline__ void cacc(v2& acc, v2 w, v2 p){
    asm("v_pk_fma_f32 %0, %1, %2, %0 op_sel:[0,0,0] op_sel_hi:[1,0,1]"
        : "+v"(acc) : "s"(w), "v"(p));
    asm("v_pk_fma_f32 %0, %1, %2, %0 op_sel:[1,1,0] op_sel_hi:[0,1,1] neg_hi:[0,1,0]"
        : "+v"(acc) : "s"(w), "v"(p));
}
// acc += w * (p.x, -p.y), real w (pair {w,w} in SGPRs): 1 pk_fma
__device__ __forceinline__ void racc(v2& acc, v2 wp, v2 p){
    asm("v_pk_fma_f32 %0, %1, %2, %0 op_sel:[0,0,0] op_sel_hi:[1,1,1] neg_hi:[0,1,0]"
        : "+v"(acc) : "s"(wp), "v"(p));
}

// XOR bank swizzle: float2 elements -> bank = (2e)%32 depends on e mod 16.
// SW changes bits 0-3 only => every address stays inside its aligned
// 512-element region (wave-ownership argument relies on this).
__device__ __forceinline__ int SW(int e){ return e ^ (((e>>5) ^ (e>>9)) & 15); }

// ---- cheap-address forms of SW for the structured access patterns ----
//   SW(tid+512k) = (tid ^ ((tid>>5)&15) ^ k) + 512k
// Byte address = (tbs ^ (k<<3)) + (k<<12) with tbs = (tid ^ ((tid>>5)&15))<<3.
__device__ __forceinline__ v2& q512(v2* buf, int tbs, int k){
    return *(v2*)((char*)buf + ((tbs ^ (k<<3)) + (k<<12)));
}
// Upper half (+4096 elems): mask ^= 8 -> byte^=64, + 32768 byte offset.
__device__ __forceinline__ v2& q512u(v2* buf, int tbs, int k){
    return *(v2*)((char*)buf + (((tbs ^ 64) ^ (k<<3)) + (k<<12) + 32768));
}

// base-8 digit reversal of a 12-bit index
__device__ __forceinline__ int d8r4(int x){
    return ((x&7)<<9) | (((x>>3)&7)<<6) | (((x>>6)&7)<<3) | ((x>>9)&7);
}
// base-8 digit reversal of a 9-bit index (thread id <-> butterfly block)
__device__ __forceinline__ int rev3(int t){
    return ((t&7)<<6) | (t&56) | ((t>>6)&7);
}

// ---- load one 7-twiddle row (padded to 8 v2 = 64B) from the global table.
__device__ __forceinline__ void load_row(const v2* twd, int rowIdx, v2 W[7]) {
    const float4* rp4 = (const float4*)(twd + rowIdx*8);
    float4 q0 = rp4[0], q1 = rp4[1], q2 = rp4[2], q3 = rp4[3];
    W[0]=(v2){q0.x,q0.y}; W[1]=(v2){q0.z,q0.w}; W[2]=(v2){q1.x,q1.y};
    W[3]=(v2){q1.z,q1.w}; W[4]=(v2){q2.x,q2.y}; W[5]=(v2){q2.z,q2.w};
    W[6]=(v2){q3.x,q3.y};
}

// ---- 8-point DFT, inverse sign (sigma=+1). y_m = sum_k t_k w^{mk}, w=e^{+i pi/4}
__device__ __forceinline__ void dft8_inv(v2 t[8], v2 y[8]) {
    const float RH = 0.70710678f;
    v2 p  = t[0]+t[4], m  = t[0]-t[4], q  = t[2]+t[6], r  = t[2]-t[6];
    v2 E0 = p+q, E2 = p-q;
    v2 E1 = pk_addrot(m, r), E3 = pk_subrot(m, r);
    v2 p2 = t[1]+t[5], m2 = t[1]-t[5], q2 = t[3]+t[7], r2 = t[3]-t[7];
    v2 O0 = p2+q2, O2 = p2-q2;
    v2 O1 = pk_addrot(m2, r2), O3 = pk_subrot(m2, r2);
    v2 W1O = RH * pk_addrot(O1, O1);          // w^1 * O1
    v2 A3  = RH * pk_addrot(O3, O3);          // w^3*O3 = i*A3
    y[0] = E0 + O0;  y[4] = E0 - O0;
    y[1] = E1 + W1O; y[5] = E1 - W1O;
    y[2] = pk_addrot(E2, O2); y[6] = pk_subrot(E2, O2);   // w^2 = i
    y[3] = pk_addrot(E3, A3); y[7] = pk_subrot(E3, A3);
}

// ---- pruned: only y[0..3] (P7 epilogue discards the mirror half).
__device__ __forceinline__ void dft8_inv_lo4(v2 t[8], v2 y[4]) {
    const float RH = 0.70710678f;
    v2 p  = t[0]+t[4], m  = t[0]-t[4], q  = t[2]+t[6], r  = t[2]-t[6];
    v2 E0 = p+q, E2 = p-q;
    v2 E1 = pk_addrot(m, r), E3 = pk_subrot(m, r);
    v2 p2 = t[1]+t[5], m2 = t[1]-t[5], q2 = t[3]+t[7], r2 = t[3]-t[7];
    v2 O0 = p2+q2, O2 = p2-q2;
    v2 O1 = pk_addrot(m2, r2), O3 = pk_subrot(m2, r2);
    v2 W1O = RH * pk_addrot(O1, O1);
    v2 A3  = RH * pk_addrot(O3, O3);
    y[0] = E0 + O0;
    y[1] = E1 + W1O;
    y[2] = pk_addrot(E2, O2);
    y[3] = pk_addrot(E3, A3);
}

// ---- 8-point DFT, forward sign (sigma=-1).
__device__ __forceinline__ void dft8_fwd(v2 t[8], v2 y[8]) {
    const float RH = 0.70710678f;
    v2 p  = t[0]+t[4], m  = t[0]-t[4], q  = t[2]+t[6], r  = t[2]-t[6];
    v2 E0 = p+q, E2 = p-q;
    v2 E1 = pk_subrot(m, r), E3 = pk_addrot(m, r);
    v2 p2 = t[1]+t[5], m2 = t[1]-t[5], q2 = t[3]+t[7], r2 = t[3]-t[7];
    v2 O0 = p2+q2, O2 = p2-q2;
    v2 O1 = pk_subrot(m2, r2), O3 = pk_addrot(m2, r2);
    v2 W1O = RH * pk_subrot(O1, O1);          // w = (1-i)/sqrt2
    v2 A3f = RH * pk_addrot(O3, O3);          // w^3*O3 = -A3f
    y[0] = E0 + O0;  y[4] = E0 - O0;
    y[1] = E1 + W1O; y[5] = E1 - W1O;
    y[2] = pk_subrot(E2, O2); y[6] = pk_addrot(E2, O2);   // w^2 = -i
    y[3] = E3 - A3f; y[7] = E3 + A3f;
}

// Wave-locality: for Q in {1,8,64}, thread t's butterfly addresses lie in the
// aligned 512-elem region [512*(t>>6), +512), owned exclusively by t's wave.

// ---- radix-8 DIT pass, inverse, in-place over 4096 elems.
template<int Q, bool BAR>
__device__ __forceinline__ void r8_dit_inv(v2* buf, int tid, const v2* twd) {
    int j = tid & (Q-1);
    v2 W[7];
    load_row(twd, (512/Q)*j, W);       // issue vmem first, overlap with LDS reads
    int base = 8*tid - 7*j;
    v2 t[8];
    #pragma unroll
    for (int k = 0; k < 8; ++k) t[k] = buf[SW(base + k*Q)];
    #pragma unroll
    for (int k = 0; k < 7; ++k) t[k+1] = vcmul(t[k+1], W[k]);
    v2 y[8];
    dft8_inv(t, y);
    #pragma unroll
    for (int m = 0; m < 8; ++m) buf[SW(base + m*Q)] = y[m];
    if (BAR) __syncthreads();
    else     __builtin_amdgcn_wave_barrier();
}

// ---- radix-8 DIF pass, forward, applied to BOTH 4096-halves of buf (serial).
template<int Q, bool BAR>
__device__ __forceinline__ void r8_dif_fwd(v2* buf, int tid, const v2* twd) {
    if (Q == 1) {
        const int b0  = tid << 6;                        // (8*tid)<<3  byte base
        const int bt  = tid << 3;                        // 8*tid       element base
        const int mLs = (((bt>>5) ^ (bt>>9)) & 15) << 3; // lower-half byte mask
        const int msU = (mLs ^ 64) + 32768;              // upper: ^64, +32768
        #pragma unroll 1
        for (int hh = 0; hh < 2; ++hh) {
            const int ms = hh ? msU : mLs;
            v2 t[8];
            #pragma unroll
            for (int k = 0; k < 8; ++k)
                t[k] = *(v2*)((char*)buf + ((b0 + (k<<3)) ^ ms));
            v2 y[8];
            dft8_fwd(t, y);
            #pragma unroll
            for (int m = 0; m < 8; ++m)
                *(v2*)((char*)buf + ((b0 + (m<<3)) ^ ms)) = y[m];
        }
        if (BAR) __syncthreads();
        else     __builtin_amdgcn_wave_barrier();
        return;
    }
    int j = tid & (Q-1);
    int baseL = 8*tid - 7*j;
    v2 W[7];
    load_row(twd, (512/Q)*j, W);
    #pragma unroll 1
    for (int hh = 0; hh < 2; ++hh) {
        int base = baseL + (hh << 12);
        v2 t[8];
        #pragma unroll
        for (int k = 0; k < 8; ++k) t[k] = buf[SW(base + k*Q)];
        v2 y[8];
        dft8_fwd(t, y);
        #pragma unroll
        for (int k = 0; k < 7; ++k) y[k+1] = vcmulc(y[k+1], W[k]);
        #pragma unroll
        for (int m = 0; m < 8; ++m) buf[SW(base + m*Q)] = y[m];
    }
    if (BAR) __syncthreads();
    else     __builtin_amdgcn_wave_barrier();
}

// ---- merged prep kernel: blocks 0..H-1 compute per-(h,n) Cauchy weights;
//      the LAST block (blockIdx == H) fills the twiddle table.
__global__ void __launch_bounds__(64)
s4_prep(const float* __restrict__ Lre, const float* __restrict__ Lim,
        const float* __restrict__ Pre, const float* __restrict__ Pim,
        const float* __restrict__ Bre, const float* __restrict__ Bim,
        const float* __restrict__ Cin,
        float* __restrict__ ws8, float* __restrict__ ws1,
        v2* __restrict__ twd)
{
    int b = blockIdx.x;
    if (b == (int)gridDim.x - 1) {
        // twiddle block: 64 threads x 8 rows
        const float fm = 6.2831853072f / 4096.0f;
        #pragma unroll
        for (int r = 0; r < 8; ++r) {
            int j = r*64 + (int)threadIdx.x;
            #pragma unroll
            for (int k = 0; k < 7; ++k) {
                float s, c; __sincosf(fm * (float)(j*(k+1)), &s, &c);
                twd[j*8 + k] = (v2){c, s};
            }
            twd[j*8 + 7] = (v2){1.0f, 0.0f};
        }
        return;
    }
    int idx = b*64 + threadIdx.x;   // h*64 + n
    float lre = fminf(Lre[idx], -1e-4f);
    float lim = Lim[idx];
    float pr = Pre[idx], pi = Pim[idx];
    float br = Bre[idx], bi = Bim[idx];
    float cr = Cin[2*idx], ci = Cin[2*idx+1];
    v2 cc = (v2){cr, -ci};
    v2 w00 = vcmul(cc, (v2){br, bi});     // conj(C)*B
    v2 w01 = vcmul(cc, (v2){pr, pi});     // conj(C)*P
    v2 w10 = vcmul((v2){pr,-pi}, (v2){br, bi});  // conj(P)*B
    float* o = ws8 + idx*8;
    o[0] = -lre;  o[1] = -lim;
    o[2] = w00.x; o[3] = w00.y;
    o[4] = w01.x; o[5] = w01.y;
    o[6] = w10.x; o[7] = w10.y;
    ws1[idx] = pr*pr + pi*pi;             // |P|^2 (real weight of k11)
}

// Fused S4 layer, one block per channel h. R3 structure (92 us); this round:
// all hot complex arithmetic forced to modifier-folded v_pk_*_f32 (VOP3P)
// via inline asm -- 2 insts per complex MAC, 1 per rotate-combine, weights
// consumed directly from SGPRs. No new live state (no spill risk).
__global__ __attribute__((amdgpu_waves_per_eu(4, 4))) void __launch_bounds__(NT)
s4_fused(const float* __restrict__ u,
         const float* __restrict__ Din, const float* __restrict__ logstep,
         const float* __restrict__ ws8, const float* __restrict__ ws1,
         const v2* __restrict__ twd,
         float* __restrict__ out)
{
    __shared__ v2 buf[8192];   // 64 KB -> 2 blocks/CU
    const int tid = threadIdx.x;
    const int h = blockIdx.x;
    const int tbs = (tid ^ ((tid>>5) & 15)) << 3;   // stride-512 swizzle byte base

    const float step = expf(logstep[h]);
    const float tos  = 2.0f / step;
    const float hstep = 0.5f * step;
    const float* pp = ws8 + (h*64)*8;   // wave-uniform -> s_load
    const float* pw = ws1 + h*64;
    const float4* pp4 = (const float4*)pp;   // 2 float4 per n

    // ---- P1: Cauchy kernel; hp0's 4 results staged raw in LDS, hp1's kept in
    //      regs; then the P2 Q=1 butterfly runs in registers. ----
    v2 a4[4];
    #pragma unroll 1
    for (int hp = 0; hp < 2; ++hp) {
        float tv[4];
        v2 cf[4], k00[4], k01[4], k10[4], k11[4];
        const int lbase = hp*(4*NT);
        #pragma unroll
        for (int i = 0; i < 4; ++i) {
            int l = lbase + i*NT + tid;
            // reference's f32 angle; g = i*t with t = -tos*tan(ang/2)
            float ang = -6.2831855f * ((float)l * (1.0f/4096.0f));
            float sh, ch; __sincosf(0.5f*ang, &sh, &ch);
            float traw = -tos * sh * __builtin_amdgcn_rcpf(ch);
            float t = fminf(fmaxf(traw, -1e18f), 1e18f);   // guard cos==0 -> inf*0 NaN
            tv[i] = t;
            cf[i] = (v2){1.0f, t*hstep};                   // c = 1 - i*tan(ang/2)
            k00[i]=(v2)(0.0f); k01[i]=(v2)(0.0f); k10[i]=(v2)(0.0f); k11[i]=(v2)(0.0f);
        }
        #pragma unroll 4
        for (int n = 0; n < 64; ++n) {
            float4 A = pp4[2*n], B = pp4[2*n+1];           // s_load_dwordx4 pair
            float nlre = A.x, nlim = A.y;
            v2 w00 = (v2){A.z, A.w};
            v2 w01 = (v2){B.x, B.y};
            v2 w10 = (v2){B.z, B.w};
            float w11r = pw[n];
            v2 w11p = (v2){w11r, w11r};
            float lre2 = nlre*nlre;
            #pragma unroll
            for (int i = 0; i < 4; ++i) {
                float s = tv[i] + nlim;                    // t - lim
                float inv = __builtin_amdgcn_rcpf(__builtin_fmaf(s, s, lre2));
                v2 p; p.x = nlre * inv; p.y = s * inv;     // p = conj(1/d)~, d=(-lre, s)
                cacc(k00[i], w00, p);                      // k += w * (p.x,-p.y)
                cacc(k01[i], w01, p);
                cacc(k10[i], w10, p);
                racc(k11[i], w11p, p);
            }
        }
        #pragma unroll
        for (int i = 0; i < 4; ++i) {
            v2 opk = (v2){1.0f + k11[i].x, k11[i].y};
            float iv = __builtin_amdgcn_rcpf(opk.x*opk.x + opk.y*opk.y);
            v2 r11 = vconj(opk) * iv;
            v2 t  = vcmul(vcmul(k01[i], r11), k10[i]);
            v2 res = vcmul(cf[i], k00[i] - t);             // atRoots[l], l = tid+512*(4hp+i)
            if (hp == 0) q512(buf, tbs, i) = res;          // stage raw
            else         a4[i] = res;
        }
    }
    {   // fused P2 Q=1 butterfly: t[k] = atRoots[tid + 512k]
        v2 t[8];
        #pragma unroll
        for (int k = 0; k < 4; ++k) t[k] = q512(buf, tbs, k);   // own raw stage
        #pragma unroll
        for (int k = 0; k < 4; ++k) t[4+k] = a4[k];
        __syncthreads();                    // all raw reads done before any butterfly write
        v2 y[8];
        dft8_inv(t, y);
        const int tb8 = 8*rev3(tid);
        const int b8  = tb8 << 3;
        const int m8s = (((tb8>>5) ^ (tb8>>9)) & 15) << 3;
        #pragma unroll
        for (int m = 0; m < 8; ++m)
            *(v2*)((char*)buf + ((b8 + (m<<3)) ^ m8s)) = y[m];
    }
    __syncthreads();                        // Q1 scatter is cross-wave

    // ---- P2: ifft4096 middle passes (Q8->Q64 wave-local) ----
    r8_dit_inv<8,  false>(buf, tid, twd);
    r8_dit_inv<64, true >(buf, tid, twd);

    // ---- P3: fused P2-Q512 (DIT) + pack z = u + i*K + r2 stage + DIF-Q512. ----
    {
        v2 W[7];
        load_row(twd, tid, W);              // W[k] = W_4096^{+tid(k+1)}
        v2 t[8];
        #pragma unroll
        for (int k = 0; k < 8; ++k) t[k] = q512(buf, tbs, k);
        #pragma unroll
        for (int k = 0; k < 7; ++k) t[k+1] = vcmul(t[k+1], W[k]);
        v2 y[8];
        dft8_inv(t, y);                          // y[m].x = K*4096 at l = tid+512m
        float uval[8];
        const float* up = u + h*4096;
        #pragma unroll
        for (int m = 0; m < 8; ++m) uval[m] = up[tid + 512*m];
        float s2, c2; __sincosf(-6.2831853072f/8192.0f*(float)tid, &s2, &c2);
        v2 cur0 = (v2){c2, s2};                  // W_8192^{-tid}
        const v2 C16n = (v2){0.92387953f, -0.38268343f};   // e^{-i pi/8}
        v2 zL[8], zU[8];
        {
            v2 cur = cur0;
            #pragma unroll
            for (int k = 0; k < 8; ++k) {
                zL[k] = (v2){uval[k], y[k].x * (1.0f/4096.0f)};
                zU[k] = vcmul(zL[k], cur);
                cur = vcmul(cur, C16n);
            }
        }
        v2 s[8];
        dft8_fwd(zL, s);
        #pragma unroll
        for (int m = 1; m < 8; ++m) s[m] = vcmulc(s[m], W[m-1]);
        #pragma unroll
        for (int m = 0; m < 8; ++m) q512(buf, tbs, m) = s[m];
        dft8_fwd(zU, s);
        #pragma unroll
        for (int m = 1; m < 8; ++m) s[m] = vcmulc(s[m], W[m-1]);
        #pragma unroll
        for (int m = 0; m < 8; ++m) q512u(buf, tbs, m) = s[m];
    }
    __syncthreads();                        // Q512 writes are cross-wave for Q64

    // ---- P4: forward fft8192 remaining stages ----
    r8_dif_fwd<64, false>(buf, tid, twd);
    r8_dif_fwd<8,  false>(buf, tid, twd);
    r8_dif_fwd<1,  true >(buf, tid, twd);

    // ---- P5: unpack + multiply + half-size-inverse pack, fused with P6 Q=1
    //      butterfly. ----
    {
        float sb, cb; __sincosf(6.2831853072f/8192.0f*(float)tid, &sb, &cb);
        v2 cur = (v2){cb, sb};                   // W_8192^{+tid}
        const v2 C16p = (v2){0.92387953f, 0.38268343f};    // e^{+i pi/8}
        v2 v[8];
        #pragma unroll 1
        for (int i = 0; i < 8; ++i) {
            int r  = i*NT + tid;                 // 0..4095
            int par = (r&1)<<12;
            int e1 = par + d8r4(r>>1);           // za: Z[r]
            int e3 = e1 + 4;                     // zc: Z[r+4096]
            int k2c = 4096 - r;
            int e4 = ((k2c&1)<<12) + d8r4((k2c>>1)&4095);  // zd: Z[4096-r]
            int e2 = (r == 0) ? 0 : (e4 + 4);    // zb: Z[(8192-r)&8191]
            v2 za = buf[SW(e1)];
            v2 zb = buf[SW(e2)];
            v2 zc = buf[SW(e3)];
            v2 zd = buf[SW(e4)];
            v2 U1 = 0.5f*(za + vconj(zb));
            v2 K1 = -0.5f*vrot(za - vconj(zb));
            v2 Yr = vcmul(U1, K1);                               // Y[r]
            v2 U2 = 0.5f*(zc + vconj(zd));
            v2 K2 = -0.5f*vrot(zc - vconj(zd));
            v2 Ys = vcmul(U2, K2);                               // Y[r+4096]
            v[i] = pk_addrot(Yr + Ys, vcmul(cur, Yr - Ys));      // A + i*W^r*(Yr-Ys)
            cur = vcmul(cur, C16p);
        }
        __syncthreads();                         // all gathers done before butterfly writes
        v2 y[8];
        dft8_inv(v, y);
        const int tb8 = 8*rev3(tid);
        const int b8  = tb8 << 3;
        const int m8s = (((tb8>>5) ^ (tb8>>9)) & 15) << 3;
        #pragma unroll
        for (int m = 0; m < 8; ++m)
            *(v2*)((char*)buf + ((b8 + (m<<3)) ^ m8s)) = y[m];
    }
    __syncthreads();                        // Q1 scatter is cross-wave

    // ---- P6: ifft4096 middle passes ----
    r8_dit_inv<8,  false>(buf, tid, twd);
    r8_dit_inv<64, true >(buf, tid, twd);

    // ---- P7: fused P6-Q512 butterfly + epilogue. ----
    {
        v2 W[7];
        load_row(twd, tid, W);
        v2 t[8];
        #pragma unroll
        for (int k = 0; k < 8; ++k) t[k] = q512(buf, tbs, k);
        #pragma unroll
        for (int k = 0; k < 7; ++k) t[k+1] = vcmul(t[k+1], W[k]);
        v2 y[4];
        dft8_inv_lo4(t, y);
        const float Dh = Din[h];
        const float sc = 1.0f / 8192.0f;
        const v2* u2 = (const v2*)(u + h*4096);
        v2*     out2 = (v2*)(out + h*4096);
        #pragma unroll
        for (int m = 0; m < 4; ++m) {
            int n = tid + 512*m;                 // v2-pair index -> outputs 2n, 2n+1
            out2[n] = sc*y[m] + Dh*u2[n];
        }
    }
}

extern "C" void kernel_launch(void* const* d_in, const int* in_sizes, int n_in,
                              void* d_out, int out_size, void* d_ws, size_t ws_size,
                              hipStream_t stream)
{
    const float* u       = (const float*)d_in[0];
    const float* Lre     = (const float*)d_in[1];
    const float* Lim     = (const float*)d_in[2];
    const float* Pre     = (const float*)d_in[3];
    const float* Pim     = (const float*)d_in[4];
    const float* Bre     = (const float*)d_in[5];
    const float* Bim     = (const float*)d_in[6];
    const float* Cin     = (const float*)d_in[7];
    const float* Din     = (const float*)d_in[8];
    const float* logstep = (const float*)d_in[9];
    float* out = (float*)d_out;
    const int H = in_sizes[8];  // D is [H,1]

    float* ws8 = (float*)d_ws;            // H*64*8 floats (1 MB)
    float* ws1 = ws8 + (size_t)H*64*8;    // H*64 floats (128 KB)
    v2*    twd = (v2*)(ws1 + (size_t)H*64);  // 512 rows x 8 v2 (32 KB); 64B-aligned

    // merged prep: blocks 0..H-1 per-(h,n) weights; block H fills twiddles
    hipLaunchKernelGGL(s4_prep, dim3(H + 1), dim3(64), 0, stream,
                       Lre, Lim, Pre, Pim, Bre, Bim, Cin, ws8, ws1, twd);
    hipLaunchKernelGGL(s4_fused, dim3(H), dim3(NT), 0, stream,
                       u, Din, logstep, ws8, ws1, twd, out);
}

// Round 7
// 144.306 us; speedup vs baseline: 1.1385x; 1.0221x over previous
//
#include <hip/hip_runtime.h>
#include <math.h>

#define NT 512   // threads per block; 512 blocks (one per channel h)

// Packed f32 pair. All hot complex math is explicit VOP3P (v_pk_*_f32) inline
// asm with op_sel/neg modifiers. op_sel[i] picks the 32-bit word of src i for
// the LOW result half (0=lo), op_sel_hi[i] for the HIGH half (0=lo!) --
// convention validated on HW in R6.
typedef float v2 __attribute__((ext_vector_type(2)));

__device__ __forceinline__ v2 vrot(v2 a){ return (v2){-a.y, a.x}; }            // i*a
__device__ __forceinline__ v2 vconj(v2 a){ return (v2){a.x, -a.y}; }

// a + i*b : (a.x - b.y, a.y + b.x) -- one v_pk_add_f32
__device__ __forceinline__ v2 pk_addrot(v2 a, v2 b){
    v2 d;
    asm("v_pk_add_f32 %0, %1, %2 op_sel:[0,1] op_sel_hi:[1,0] neg_lo:[0,1] neg_hi:[0,0]"
        : "=v"(d) : "v"(a), "v"(b));
    return d;
}
// a - i*b : (a.x + b.y, a.y - b.x)
__device__ __forceinline__ v2 pk_subrot(v2 a, v2 b){
    v2 d;
    asm("v_pk_add_f32 %0, %1, %2 op_sel:[0,1] op_sel_hi:[1,0] neg_lo:[0,0] neg_hi:[0,1]"
        : "=v"(d) : "v"(a), "v"(b));
    return d;
}
// complex a*b: mul (a.x*b.x, a.x*b.y) then fma (+= -a.y*b.y, += a.y*b.x)
__device__ __forceinline__ v2 vcmul(v2 a, v2 b){
    v2 d;
    asm("v_pk_mul_f32 %0, %1, %2 op_sel:[0,0] op_sel_hi:[0,1]"
        : "=v"(d) : "v"(a), "v"(b));
    asm("v_pk_fma_f32 %0, %1, %2, %0 op_sel:[1,1,0] op_sel_hi:[1,0,1] neg_lo:[0,1,0] neg_hi:[0,0,0]"
        : "+v"(d) : "v"(a), "v"(b));
    return d;
}
// complex a*conj(b)
__device__ __forceinline__ v2 vcmulc(v2 a, v2 b){
    v2 d;
    asm("v_pk_mul_f32 %0, %1, %2 op_sel:[0,0] op_sel_hi:[0,1] neg_lo:[0,0] neg_hi:[0,1]"
        : "=v"(d) : "v"(a), "v"(b));
    asm("v_pk_fma_f32 %0, %1, %2, %0 op_sel:[1,1,0] op_sel_hi:[1,0,1]"
        : "+v"(d) : "v"(a), "v"(b));
    return d;
}

// ---- P1 packed-denominator helpers (pair over two i-lanes) ----
// (a.lo + s.hi, a.hi + s.hi)   [broadcast s.hi; s is an SGPR pair]
__device__ __forceinline__ v2 pk_add_bh(v2 a, v2 s){
    v2 d;
    asm("v_pk_add_f32 %0, %1, %2 op_sel:[0,1] op_sel_hi:[1,1]"
        : "=v"(d) : "v"(a), "s"(s));
    return d;
}
// (a.lo*a.lo + s.hi, a.hi*a.hi + s.hi)   [d = s^2 + lre^2 pairwise]
__device__ __forceinline__ v2 pk_fma_sq_bh(v2 a, v2 s){
    v2 d;
    asm("v_pk_fma_f32 %0, %1, %1, %2 op_sel:[0,0,1] op_sel_hi:[1,1,1]"
        : "=v"(d) : "v"(a), "s"(s));
    return d;
}
// (a.hi*a.lo, a.lo*a.hi)  -- cross product d0*d1 in both halves
__device__ __forceinline__ v2 pk_mul_cross(v2 a){
    v2 d;
    asm("v_pk_mul_f32 %0, %1, %1 op_sel:[1,0] op_sel_hi:[0,1]"
        : "=v"(d) : "v"(a));
    return d;
}
// (rr.lo*dd.hi, rr.lo*dd.lo)  -- Montgomery reconstruct, R in lo half
__device__ __forceinline__ v2 pk_inv_lo(v2 rr, v2 dd){
    v2 d;
    asm("v_pk_mul_f32 %0, %1, %2 op_sel:[0,1] op_sel_hi:[0,0]"
        : "=v"(d) : "v"(rr), "v"(dd));
    return d;
}
// (rr.hi*dd.hi, rr.hi*dd.lo)  -- R in hi half
__device__ __forceinline__ v2 pk_inv_hi(v2 rr, v2 dd){
    v2 d;
    asm("v_pk_mul_f32 %0, %1, %2 op_sel:[1,1] op_sel_hi:[1,0]"
        : "=v"(d) : "v"(rr), "v"(dd));
    return d;
}
// (a.lo*s.lo, a.hi*s.lo)   [broadcast s.lo from SGPR pair]
__device__ __forceinline__ v2 pk_mul_bl(v2 a, v2 s){
    v2 d;
    asm("v_pk_mul_f32 %0, %1, %2 op_sel:[0,0] op_sel_hi:[1,0]"
        : "=v"(d) : "v"(a), "s"(s));
    return d;
}
// plain packed multiply (VGPR x VGPR)
__device__ __forceinline__ v2 pk_mulp(v2 a, v2 b){
    v2 d;
    asm("v_pk_mul_f32 %0, %1, %2 op_sel:[0,0] op_sel_hi:[1,1]"
        : "=v"(d) : "v"(a), "v"(b));
    return d;
}
// transposed accumulate: acc += bcast_lo(w) * p      [w is SGPR pair]
__device__ __forceinline__ void fmaBlo(v2& acc, v2 w, v2 p){
    asm("v_pk_fma_f32 %0, %1, %2, %0 op_sel:[0,0,0] op_sel_hi:[0,1,1]"
        : "+v"(acc) : "s"(w), "v"(p));
}
// acc += bcast_hi(w) * p
__device__ __forceinline__ void fmaBhi(v2& acc, v2 w, v2 p){
    asm("v_pk_fma_f32 %0, %1, %2, %0 op_sel:[1,0,0] op_sel_hi:[1,1,1]"
        : "+v"(acc) : "s"(w), "v"(p));
}
// acc -= bcast_lo(w) * p
__device__ __forceinline__ void fmaBlon(v2& acc, v2 w, v2 p){
    asm("v_pk_fma_f32 %0, %1, %2, %0 op_sel:[0,0,0] op_sel_hi:[0,1,1] neg_lo:[1,0,0] neg_hi:[1,0,0]"
        : "+v"(acc) : "s"(w), "v"(p));
}

// XOR bank swizzle: float2 elements -> bank = (2e)%32 depends on e mod 16.
__device__ __forceinline__ int SW(int e){ return e ^ (((e>>5) ^ (e>>9)) & 15); }

// ---- cheap-address forms of SW for the structured access patterns ----
//   SW(tid+512k) = (tid ^ ((tid>>5)&15) ^ k) + 512k
__device__ __forceinline__ v2& q512(v2* buf, int tbs, int k){
    return *(v2*)((char*)buf + ((tbs ^ (k<<3)) + (k<<12)));
}
__device__ __forceinline__ v2& q512u(v2* buf, int tbs, int k){
    return *(v2*)((char*)buf + (((tbs ^ 64) ^ (k<<3)) + (k<<12) + 32768));
}

// base-8 digit reversal of a 12-bit index
__device__ __forceinline__ int d8r4(int x){
    return ((x&7)<<9) | (((x>>3)&7)<<6) | (((x>>6)&7)<<3) | ((x>>9)&7);
}
// base-8 digit reversal of a 9-bit index (thread id <-> butterfly block)
__device__ __forceinline__ int rev3(int t){
    return ((t&7)<<6) | (t&56) | ((t>>6)&7);
}

// ---- load one 7-twiddle row (padded to 8 v2 = 64B) from the global table.
__device__ __forceinline__ void load_row(const v2* twd, int rowIdx, v2 W[7]) {
    const float4* rp4 = (const float4*)(twd + rowIdx*8);
    float4 q0 = rp4[0], q1 = rp4[1], q2 = rp4[2], q3 = rp4[3];
    W[0]=(v2){q0.x,q0.y}; W[1]=(v2){q0.z,q0.w}; W[2]=(v2){q1.x,q1.y};
    W[3]=(v2){q1.z,q1.w}; W[4]=(v2){q2.x,q2.y}; W[5]=(v2){q2.z,q2.w};
    W[6]=(v2){q3.x,q3.y};
}

// ---- 8-point DFT, inverse sign (sigma=+1). y_m = sum_k t_k w^{mk}, w=e^{+i pi/4}
__device__ __forceinline__ void dft8_inv(v2 t[8], v2 y[8]) {
    const float RH = 0.70710678f;
    v2 p  = t[0]+t[4], m  = t[0]-t[4], q  = t[2]+t[6], r  = t[2]-t[6];
    v2 E0 = p+q, E2 = p-q;
    v2 E1 = pk_addrot(m, r), E3 = pk_subrot(m, r);
    v2 p2 = t[1]+t[5], m2 = t[1]-t[5], q2 = t[3]+t[7], r2 = t[3]-t[7];
    v2 O0 = p2+q2, O2 = p2-q2;
    v2 O1 = pk_addrot(m2, r2), O3 = pk_subrot(m2, r2);
    v2 W1O = RH * pk_addrot(O1, O1);          // w^1 * O1
    v2 A3  = RH * pk_addrot(O3, O3);          // w^3*O3 = i*A3
    y[0] = E0 + O0;  y[4] = E0 - O0;
    y[1] = E1 + W1O; y[5] = E1 - W1O;
    y[2] = pk_addrot(E2, O2); y[6] = pk_subrot(E2, O2);   // w^2 = i
    y[3] = pk_addrot(E3, A3); y[7] = pk_subrot(E3, A3);
}

// ---- pruned: only y[0..3] (P7 epilogue discards the mirror half).
__device__ __forceinline__ void dft8_inv_lo4(v2 t[8], v2 y[4]) {
    const float RH = 0.70710678f;
    v2 p  = t[0]+t[4], m  = t[0]-t[4], q  = t[2]+t[6], r  = t[2]-t[6];
    v2 E0 = p+q, E2 = p-q;
    v2 E1 = pk_addrot(m, r), E3 = pk_subrot(m, r);
    v2 p2 = t[1]+t[5], m2 = t[1]-t[5], q2 = t[3]+t[7], r2 = t[3]-t[7];
    v2 O0 = p2+q2, O2 = p2-q2;
    v2 O1 = pk_addrot(m2, r2), O3 = pk_subrot(m2, r2);
    v2 W1O = RH * pk_addrot(O1, O1);
    v2 A3  = RH * pk_addrot(O3, O3);
    y[0] = E0 + O0;
    y[1] = E1 + W1O;
    y[2] = pk_addrot(E2, O2);
    y[3] = pk_addrot(E3, A3);
}

// ---- 8-point DFT, forward sign (sigma=-1).
__device__ __forceinline__ void dft8_fwd(v2 t[8], v2 y[8]) {
    const float RH = 0.70710678f;
    v2 p  = t[0]+t[4], m  = t[0]-t[4], q  = t[2]+t[6], r  = t[2]-t[6];
    v2 E0 = p+q, E2 = p-q;
    v2 E1 = pk_subrot(m, r), E3 = pk_addrot(m, r);
    v2 p2 = t[1]+t[5], m2 = t[1]-t[5], q2 = t[3]+t[7], r2 = t[3]-t[7];
    v2 O0 = p2+q2, O2 = p2-q2;
    v2 O1 = pk_subrot(m2, r2), O3 = pk_addrot(m2, r2);
    v2 W1O = RH * pk_subrot(O1, O1);          // w = (1-i)/sqrt2
    v2 A3f = RH * pk_addrot(O3, O3);          // w^3*O3 = -A3f
    y[0] = E0 + O0;  y[4] = E0 - O0;
    y[1] = E1 + W1O; y[5] = E1 - W1O;
    y[2] = pk_subrot(E2, O2); y[6] = pk_addrot(E2, O2);   // w^2 = -i
    y[3] = E3 - A3f; y[7] = E3 + A3f;
}

// Wave-locality: for Q in {1,8,64}, thread t's butterfly addresses lie in the
// aligned 512-elem region [512*(t>>6), +512), owned exclusively by t's wave.

// ---- radix-8 DIT pass, inverse, in-place over 4096 elems.
template<int Q, bool BAR>
__device__ __forceinline__ void r8_dit_inv(v2* buf, int tid, const v2* twd) {
    int j = tid & (Q-1);
    v2 W[7];
    load_row(twd, (512/Q)*j, W);       // issue vmem first, overlap with LDS reads
    int base = 8*tid - 7*j;
    v2 t[8];
    #pragma unroll
    for (int k = 0; k < 8; ++k) t[k] = buf[SW(base + k*Q)];
    #pragma unroll
    for (int k = 0; k < 7; ++k) t[k+1] = vcmul(t[k+1], W[k]);
    v2 y[8];
    dft8_inv(t, y);
    #pragma unroll
    for (int m = 0; m < 8; ++m) buf[SW(base + m*Q)] = y[m];
    if (BAR) __syncthreads();
    else     __builtin_amdgcn_wave_barrier();
}

// ---- radix-8 DIF pass, forward, applied to BOTH 4096-halves of buf (serial).
template<int Q, bool BAR>
__device__ __forceinline__ void r8_dif_fwd(v2* buf, int tid, const v2* twd) {
    if (Q == 1) {
        const int b0  = tid << 6;                        // (8*tid)<<3  byte base
        const int bt  = tid << 3;                        // 8*tid       element base
        const int mLs = (((bt>>5) ^ (bt>>9)) & 15) << 3; // lower-half byte mask
        const int msU = (mLs ^ 64) + 32768;              // upper: ^64, +32768
        #pragma unroll 1
        for (int hh = 0; hh < 2; ++hh) {
            const int ms = hh ? msU : mLs;
            v2 t[8];
            #pragma unroll
            for (int k = 0; k < 8; ++k)
                t[k] = *(v2*)((char*)buf + ((b0 + (k<<3)) ^ ms));
            v2 y[8];
            dft8_fwd(t, y);
            #pragma unroll
            for (int m = 0; m < 8; ++m)
                *(v2*)((char*)buf + ((b0 + (m<<3)) ^ ms)) = y[m];
        }
        if (BAR) __syncthreads();
        else     __builtin_amdgcn_wave_barrier();
        return;
    }
    int j = tid & (Q-1);
    int baseL = 8*tid - 7*j;
    v2 W[7];
    load_row(twd, (512/Q)*j, W);
    #pragma unroll 1
    for (int hh = 0; hh < 2; ++hh) {
        int base = baseL + (hh << 12);
        v2 t[8];
        #pragma unroll
        for (int k = 0; k < 8; ++k) t[k] = buf[SW(base + k*Q)];
        v2 y[8];
        dft8_fwd(t, y);
        #pragma unroll
        for (int k = 0; k < 7; ++k) y[k+1] = vcmulc(y[k+1], W[k]);
        #pragma unroll
        for (int m = 0; m < 8; ++m) buf[SW(base + m*Q)] = y[m];
    }
    if (BAR) __syncthreads();
    else     __builtin_amdgcn_wave_barrier();
}

// ---- merged prep kernel: blocks 0..H-1 compute per-(h,n) Cauchy weights;
//      the LAST block (blockIdx == H) fills the twiddle table.
//      ws1 layout: 2 floats per (h,n) = (|P|^2, lre^2) -- an even-aligned
//      SGPR pair in the main kernel (broadcast sources for VOP3P).
__global__ void __launch_bounds__(64)
s4_prep(const float* __restrict__ Lre, const float* __restrict__ Lim,
        const float* __restrict__ Pre, const float* __restrict__ Pim,
        const float* __restrict__ Bre, const float* __restrict__ Bim,
        const float* __restrict__ Cin,
        float* __restrict__ ws8, float* __restrict__ ws1,
        v2* __restrict__ twd)
{
    int b = blockIdx.x;
    if (b == (int)gridDim.x - 1) {
        // twiddle block: 64 threads x 8 rows
        const float fm = 6.2831853072f / 4096.0f;
        #pragma unroll
        for (int r = 0; r < 8; ++r) {
            int j = r*64 + (int)threadIdx.x;
            #pragma unroll
            for (int k = 0; k < 7; ++k) {
                float s, c; __sincosf(fm * (float)(j*(k+1)), &s, &c);
                twd[j*8 + k] = (v2){c, s};
            }
            twd[j*8 + 7] = (v2){1.0f, 0.0f};
        }
        return;
    }
    int idx = b*64 + threadIdx.x;   // h*64 + n
    float lre = fminf(Lre[idx], -1e-4f);
    float lim = Lim[idx];
    float pr = Pre[idx], pi = Pim[idx];
    float br = Bre[idx], bi = Bim[idx];
    float cr = Cin[2*idx], ci = Cin[2*idx+1];
    v2 cc = (v2){cr, -ci};
    v2 w00 = vcmul(cc, (v2){br, bi});     // conj(C)*B
    v2 w01 = vcmul(cc, (v2){pr, pi});     // conj(C)*P
    v2 w10 = vcmul((v2){pr,-pi}, (v2){br, bi});  // conj(P)*B
    float* o = ws8 + idx*8;
    o[0] = -lre;  o[1] = -lim;
    o[2] = w00.x; o[3] = w00.y;
    o[4] = w01.x; o[5] = w01.y;
    o[6] = w10.x; o[7] = w10.y;
    ws1[2*idx]   = pr*pr + pi*pi;         // |P|^2 (real weight of k11)
    ws1[2*idx+1] = lre*lre;               // lre^2 (denominator constant)
}

// Fused S4 layer, one block per channel h. R6 structure (84.5 us) + this
// round: P1 denominator fully packed across i-pairs (pk_add/pk_fma with
// SGPR-pair broadcasts) + Montgomery-batched reciprocals (2 rcp per i-quad
// instead of 4) + transposed (X,Y)-packed accumulators (same FMA count).
// t-clamp tightened 1e18 -> 1e12 so pairwise d0*d1 products cannot overflow
// (real |t| <= ~5e10, clamp never binds on real data).
__global__ __attribute__((amdgpu_waves_per_eu(4, 4))) void __launch_bounds__(NT)
s4_fused(const float* __restrict__ u,
         const float* __restrict__ Din, const float* __restrict__ logstep,
         const float* __restrict__ ws8, const float* __restrict__ ws1,
         const v2* __restrict__ twd,
         float* __restrict__ out)
{
    __shared__ v2 buf[8192];   // 64 KB -> 2 blocks/CU
    const int tid = threadIdx.x;
    const int h = blockIdx.x;
    const int tbs = (tid ^ ((tid>>5) & 15)) << 3;   // stride-512 swizzle byte base

    const float step = expf(logstep[h]);
    const float tos  = 2.0f / step;
    const float hstep = 0.5f * step;
    const float* pp = ws8 + (h*64)*8;        // wave-uniform -> s_load
    const float4* pp4 = (const float4*)pp;   // 2 float4 per n
    const v2* pw2 = (const v2*)(ws1 + h*128);  // (w11, lre2) per n

    // ---- P1: Cauchy kernel; hp0's 4 results staged raw in LDS, hp1's kept in
    //      regs; then the P2 Q=1 butterfly runs in registers. ----
    v2 a4[4];
    #pragma unroll 1
    for (int hp = 0; hp < 2; ++hp) {
        v2 tvA, tvB;
        {
            float tv[4];
            #pragma unroll
            for (int i = 0; i < 4; ++i) {
                int l = hp*(4*NT) + i*NT + tid;
                float ang = -6.2831855f * ((float)l * (1.0f/4096.0f));
                float sh, ch; __sincosf(0.5f*ang, &sh, &ch);
                float traw = -tos * sh * __builtin_amdgcn_rcpf(ch);
                tv[i] = fminf(fmaxf(traw, -1e12f), 1e12f);  // guard cos==0
            }
            tvA = (v2){tv[0], tv[1]};
            tvB = (v2){tv[2], tv[3]};
        }
        // transposed accumulators: X = real parts packed over (i0,i1)/(i2,i3),
        // Y = imag parts. 16 v2 = 32 VGPRs (same as the per-i layout).
        v2 aX00A=(v2)(0.f), aY00A=(v2)(0.f), aX00B=(v2)(0.f), aY00B=(v2)(0.f);
        v2 aX01A=(v2)(0.f), aY01A=(v2)(0.f), aX01B=(v2)(0.f), aY01B=(v2)(0.f);
        v2 aX10A=(v2)(0.f), aY10A=(v2)(0.f), aX10B=(v2)(0.f), aY10B=(v2)(0.f);
        v2 aX11A=(v2)(0.f), aY11A=(v2)(0.f), aX11B=(v2)(0.f), aY11B=(v2)(0.f);
        #pragma unroll 2
        for (int n = 0; n < 64; ++n) {
            float4 A = pp4[2*n], Bq = pp4[2*n+1];  // s_load_dwordx4 pair
            v2 lam = (v2){A.x, A.y};     // (nlre, nlim) = (-lre, -lim)
            v2 w00 = (v2){A.z, A.w};
            v2 w01 = (v2){Bq.x, Bq.y};
            v2 w10 = (v2){Bq.z, Bq.w};
            v2 Wv  = pw2[n];             // (w11 = |P|^2, lre2)
            // s_i = tv_i + nlim ; d_i = s_i^2 + lre^2   (packed over i-pairs)
            v2 sA = pk_add_bh(tvA, lam), sB = pk_add_bh(tvB, lam);
            v2 dA = pk_fma_sq_bh(sA, Wv), dB = pk_fma_sq_bh(sB, Wv);
            // Montgomery: R = rcp(d0*d1); inv0 = R*d1, inv1 = R*d0
            v2 PA = pk_mul_cross(dA), PB = pk_mul_cross(dB);
            v2 RR;
            RR.x = __builtin_amdgcn_rcpf(PA.x);
            RR.y = __builtin_amdgcn_rcpf(PB.x);
            v2 invA = pk_inv_lo(RR, dA), invB = pk_inv_hi(RR, dB);
            // p_i = (nlre*inv_i, s_i*inv_i), packed across i: px / py pairs
            v2 pxA = pk_mul_bl(invA, lam), pxB = pk_mul_bl(invB, lam);
            v2 pyA = pk_mulp(invA, sA),    pyB = pk_mulp(invB, sB);
            // k_i += w * (px_i, -py_i):
            //   X += w.x*px + w.y*py ; Y += w.y*px - w.x*py
            fmaBlo(aX00A, w00, pxA); fmaBhi(aX00A, w00, pyA);
            fmaBhi(aY00A, w00, pxA); fmaBlon(aY00A, w00, pyA);
            fmaBlo(aX00B, w00, pxB); fmaBhi(aX00B, w00, pyB);
            fmaBhi(aY00B, w00, pxB); fmaBlon(aY00B, w00, pyB);
            fmaBlo(aX01A, w01, pxA); fmaBhi(aX01A, w01, pyA);
            fmaBhi(aY01A, w01, pxA); fmaBlon(aY01A, w01, pyA);
            fmaBlo(aX01B, w01, pxB); fmaBhi(aX01B, w01, pyB);
            fmaBhi(aY01B, w01, pxB); fmaBlon(aY01B, w01, pyB);
            fmaBlo(aX10A, w10, pxA); fmaBhi(aX10A, w10, pyA);
            fmaBhi(aY10A, w10, pxA); fmaBlon(aY10A, w10, pyA);
            fmaBlo(aX10B, w10, pxB); fmaBhi(aX10B, w10, pyB);
            fmaBhi(aY10B, w10, pxB); fmaBlon(aY10B, w10, pyB);
            fmaBlo(aX11A, Wv, pxA);  fmaBlon(aY11A, Wv, pyA);
            fmaBlo(aX11B, Wv, pxB);  fmaBlon(aY11B, Wv, pyB);
        }
        // unpack transposed accumulators -> per-i complex values
        float tvv[4] = { tvA.x, tvA.y, tvB.x, tvB.y };
        v2 k00[4] = { {aX00A.x,aY00A.x}, {aX00A.y,aY00A.y},
                      {aX00B.x,aY00B.x}, {aX00B.y,aY00B.y} };
        v2 k01[4] = { {aX01A.x,aY01A.x}, {aX01A.y,aY01A.y},
                      {aX01B.x,aY01B.x}, {aX01B.y,aY01B.y} };
        v2 k10[4] = { {aX10A.x,aY10A.x}, {aX10A.y,aY10A.y},
                      {aX10B.x,aY10B.x}, {aX10B.y,aY10B.y} };
        v2 k11[4] = { {aX11A.x,aY11A.x}, {aX11A.y,aY11A.y},
                      {aX11B.x,aY11B.x}, {aX11B.y,aY11B.y} };
        #pragma unroll
        for (int i = 0; i < 4; ++i) {
            v2 opk = (v2){1.0f + k11[i].x, k11[i].y};
            float iv = __builtin_amdgcn_rcpf(opk.x*opk.x + opk.y*opk.y);
            v2 r11 = vconj(opk) * iv;
            v2 t  = vcmul(vcmul(k01[i], r11), k10[i]);
            v2 cf = (v2){1.0f, tvv[i]*hstep};              // c = 1 - i*tan(ang/2)
            v2 res = vcmul(cf, k00[i] - t);                // atRoots[l]
            if (hp == 0) q512(buf, tbs, i) = res;          // stage raw
            else         a4[i] = res;
        }
    }
    {   // fused P2 Q=1 butterfly: t[k] = atRoots[tid + 512k]
        v2 t[8];
        #pragma unroll
        for (int k = 0; k < 4; ++k) t[k] = q512(buf, tbs, k);   // own raw stage
        #pragma unroll
        for (int k = 0; k < 4; ++k) t[4+k] = a4[k];
        __syncthreads();                    // all raw reads done before any butterfly write
        v2 y[8];
        dft8_inv(t, y);
        const int tb8 = 8*rev3(tid);
        const int b8  = tb8 << 3;
        const int m8s = (((tb8>>5) ^ (tb8>>9)) & 15) << 3;
        #pragma unroll
        for (int m = 0; m < 8; ++m)
            *(v2*)((char*)buf + ((b8 + (m<<3)) ^ m8s)) = y[m];
    }
    __syncthreads();                        // Q1 scatter is cross-wave

    // ---- P2: ifft4096 middle passes (Q8->Q64 wave-local) ----
    r8_dit_inv<8,  false>(buf, tid, twd);
    r8_dit_inv<64, true >(buf, tid, twd);

    // ---- P3: fused P2-Q512 (DIT) + pack z = u + i*K + r2 stage + DIF-Q512. ----
    {
        v2 W[7];
        load_row(twd, tid, W);              // W[k] = W_4096^{+tid(k+1)}
        v2 t[8];
        #pragma unroll
        for (int k = 0; k < 8; ++k) t[k] = q512(buf, tbs, k);
        #pragma unroll
        for (int k = 0; k < 7; ++k) t[k+1] = vcmul(t[k+1], W[k]);
        v2 y[8];
        dft8_inv(t, y);                          // y[m].x = K*4096 at l = tid+512m
        float uval[8];
        const float* up = u + h*4096;
        #pragma unroll
        for (int m = 0; m < 8; ++m) uval[m] = up[tid + 512*m];
        float s2, c2; __sincosf(-6.2831853072f/8192.0f*(float)tid, &s2, &c2);
        v2 cur0 = (v2){c2, s2};                  // W_8192^{-tid}
        const v2 C16n = (v2){0.92387953f, -0.38268343f};   // e^{-i pi/8}
        v2 zL[8], zU[8];
        {
            v2 cur = cur0;
            #pragma unroll
            for (int k = 0; k < 8; ++k) {
                zL[k] = (v2){uval[k], y[k].x * (1.0f/4096.0f)};
                zU[k] = vcmul(zL[k], cur);
                cur = vcmul(cur, C16n);
            }
        }
        v2 s[8];
        dft8_fwd(zL, s);
        #pragma unroll
        for (int m = 1; m < 8; ++m) s[m] = vcmulc(s[m], W[m-1]);
        #pragma unroll
        for (int m = 0; m < 8; ++m) q512(buf, tbs, m) = s[m];
        dft8_fwd(zU, s);
        #pragma unroll
        for (int m = 1; m < 8; ++m) s[m] = vcmulc(s[m], W[m-1]);
        #pragma unroll
        for (int m = 0; m < 8; ++m) q512u(buf, tbs, m) = s[m];
    }
    __syncthreads();                        // Q512 writes are cross-wave for Q64

    // ---- P4: forward fft8192 remaining stages ----
    r8_dif_fwd<64, false>(buf, tid, twd);
    r8_dif_fwd<8,  false>(buf, tid, twd);
    r8_dif_fwd<1,  true >(buf, tid, twd);

    // ---- P5: unpack + multiply + half-size-inverse pack, fused with P6 Q=1
    //      butterfly. ----
    {
        float sb, cb; __sincosf(6.2831853072f/8192.0f*(float)tid, &sb, &cb);
        v2 cur = (v2){cb, sb};                   // W_8192^{+tid}
        const v2 C16p = (v2){0.92387953f, 0.38268343f};    // e^{+i pi/8}
        v2 v[8];
        #pragma unroll 1
        for (int i = 0; i < 8; ++i) {
            int r  = i*NT + tid;                 // 0..4095
            int par = (r&1)<<12;
            int e1 = par + d8r4(r>>1);           // za: Z[r]
            int e3 = e1 + 4;                     // zc: Z[r+4096]
            int k2c = 4096 - r;
            int e4 = ((k2c&1)<<12) + d8r4((k2c>>1)&4095);  // zd: Z[4096-r]
            int e2 = (r == 0) ? 0 : (e4 + 4);    // zb: Z[(8192-r)&8191]
            v2 za = buf[SW(e1)];
            v2 zb = buf[SW(e2)];
            v2 zc = buf[SW(e3)];
            v2 zd = buf[SW(e4)];
            v2 U1 = 0.5f*(za + vconj(zb));
            v2 K1 = -0.5f*vrot(za - vconj(zb));
            v2 Yr = vcmul(U1, K1);                               // Y[r]
            v2 U2 = 0.5f*(zc + vconj(zd));
            v2 K2 = -0.5f*vrot(zc - vconj(zd));
            v2 Ys = vcmul(U2, K2);                               // Y[r+4096]
            v[i] = pk_addrot(Yr + Ys, vcmul(cur, Yr - Ys));      // A + i*W^r*(Yr-Ys)
            cur = vcmul(cur, C16p);
        }
        __syncthreads();                         // all gathers done before butterfly writes
        v2 y[8];
        dft8_inv(v, y);
        const int tb8 = 8*rev3(tid);
        const int b8  = tb8 << 3;
        const int m8s = (((tb8>>5) ^ (tb8>>9)) & 15) << 3;
        #pragma unroll
        for (int m = 0; m < 8; ++m)
            *(v2*)((char*)buf + ((b8 + (m<<3)) ^ m8s)) = y[m];
    }
    __syncthreads();                        // Q1 scatter is cross-wave

    // ---- P6: ifft4096 middle passes ----
    r8_dit_inv<8,  false>(buf, tid, twd);
    r8_dit_inv<64, true >(buf, tid, twd);

    // ---- P7: fused P6-Q512 butterfly + epilogue. ----
    {
        v2 W[7];
        load_row(twd, tid, W);
        v2 t[8];
        #pragma unroll
        for (int k = 0; k < 8; ++k) t[k] = q512(buf, tbs, k);
        #pragma unroll
        for (int k = 0; k < 7; ++k) t[k+1] = vcmul(t[k+1], W[k]);
        v2 y[4];
        dft8_inv_lo4(t, y);
        const float Dh = Din[h];
        const float sc = 1.0f / 8192.0f;
        const v2* u2 = (const v2*)(u + h*4096);
        v2*     out2 = (v2*)(out + h*4096);
        #pragma unroll
        for (int m = 0; m < 4; ++m) {
            int n = tid + 512*m;                 // v2-pair index -> outputs 2n, 2n+1
            out2[n] = sc*y[m] + Dh*u2[n];
        }
    }
}

extern "C" void kernel_launch(void* const* d_in, const int* in_sizes, int n_in,
                              void* d_out, int out_size, void* d_ws, size_t ws_size,
                              hipStream_t stream)
{
    const float* u       = (const float*)d_in[0];
    const float* Lre     = (const float*)d_in[1];
    const float* Lim     = (const float*)d_in[2];
    const float* Pre     = (const float*)d_in[3];
    const float* Pim     = (const float*)d_in[4];
    const float* Bre     = (const float*)d_in[5];
    const float* Bim     = (const float*)d_in[6];
    const float* Cin     = (const float*)d_in[7];
    const float* Din     = (const float*)d_in[8];
    const float* logstep = (const float*)d_in[9];
    float* out = (float*)d_out;
    const int H = in_sizes[8];  // D is [H,1]

    float* ws8 = (float*)d_ws;            // H*64*8 floats (1 MB)
    float* ws1 = ws8 + (size_t)H*64*8;    // H*64*2 floats (256 KB): (|P|^2, lre^2)
    v2*    twd = (v2*)(ws1 + (size_t)H*128);  // 512 rows x 8 v2 (32 KB); 64B-aligned

    // merged prep: blocks 0..H-1 per-(h,n) weights; block H fills twiddles
    hipLaunchKernelGGL(s4_prep, dim3(H + 1), dim3(64), 0, stream,
                       Lre, Lim, Pre, Pim, Bre, Bim, Cin, ws8, ws1, twd);
    hipLaunchKernelGGL(s4_fused, dim3(H), dim3(NT), 0, stream,
                       u, Din, logstep, ws8, ws1, twd, out);
}